// Round 2
// baseline (190.240 us; speedup 1.0000x reference)
//
#include <hip/hip_runtime.h>

typedef __attribute__((ext_vector_type(8))) short short8;
typedef __attribute__((ext_vector_type(4))) float floatx4;

// fp32 -> bf16 round-to-nearest-even (inputs finite; no NaN handling needed)
static __device__ __forceinline__ unsigned short f2bf(float f) {
    union { float f; unsigned int u; } v; v.f = f;
    unsigned int u = v.u;
    return (unsigned short)((u + 0x7FFFu + ((u >> 16) & 1u)) >> 16);
}

// Fused convert kernel:
//   blocks [0, nblk_nodes): node_emb fp32 -> bf16 (float4 -> ushort4)
//   blocks [nblk_nodes, nblk_nodes+8): W1 [256,128] fp32 -> W1^T bf16 [128,256],
//     LDS-tiled so both global read and global write are coalesced.
__global__ void cvt_kernel(const float* __restrict__ x, unsigned short* __restrict__ y,
                           int n4, const float* __restrict__ w1,
                           unsigned short* __restrict__ w1t, int nblk_nodes) {
    __shared__ unsigned short sT[32 * 130];  // 32 k-rows x 128 n, pad->stride 65 words
    if ((int)blockIdx.x < nblk_nodes) {
        int i = blockIdx.x * 256 + threadIdx.x;
        if (i >= n4) return;
        const float4 v = ((const float4*)x)[i];
        ushort4 o;
        o.x = f2bf(v.x); o.y = f2bf(v.y); o.z = f2bf(v.z); o.w = f2bf(v.w);
        ((ushort4*)y)[i] = o;
    } else {
        const int b = blockIdx.x - nblk_nodes;  // 0..7
        const int k0 = b * 32;
        const int tid = threadIdx.x;
#pragma unroll
        for (int i = 0; i < 16; i++) {          // load 32x128 floats, coalesced in n
            int idx = tid + i * 256;
            int k = idx >> 7, n = idx & 127;
            sT[k * 130 + n] = f2bf(w1[(k0 + k) * 128 + n]);
        }
        __syncthreads();
#pragma unroll
        for (int i = 0; i < 16; i++) {          // store, coalesced in k
            int idx = tid + i * 256;
            int n = idx >> 5, k = idx & 31;
            w1t[n * 256 + k0 + k] = sT[k * 130 + n];
        }
    }
}

// Main kernel: block = 512 thr (8 waves), covers 256 edges.
// wave -> edge-group g = wave>>1 (64 edges), col-half = wave&1 (64 of 128 cols).
// Per wave: 4 row-tiles x 4 col-tiles of mfma_f32_16x16x32_bf16, acc = 64 VGPR.
// B (W1^T) staged in LDS 128k-chunks with XOR slot swizzle (bank-uniform, no pad).
// __launch_bounds__(512,4): cap 128 regs -> 4 waves/SIMD (round-1 was 2: acc[4][8]
// = 128 acc regs alone capped occupancy at 20.6%).
__global__ __launch_bounds__(512, 4) void edge_mlp_kernel(
    const unsigned short* __restrict__ nodes,  // [N,128] bf16 bits
    const unsigned short* __restrict__ w1t,    // [128,256] bf16 bits (W1^T)
    const int* __restrict__ eidx,              // [2,E] int32
    const float* __restrict__ b1,              // [128]
    const float* __restrict__ w2,              // [128,2]
    const float* __restrict__ b2,              // [2]
    float* __restrict__ out,                   // [E,2]
    int E, int n_nodes)
{
    __shared__ unsigned short sB[128 * 128];   // 32KB: one BK=128 chunk, swizzled
    __shared__ float2 sP[2][256];              // 4KB: per-col-half partials

    const int tid  = threadIdx.x;
    const int lane = tid & 63;
    const int wave = tid >> 6;       // 0..7
    const int g    = wave >> 1;      // edge group 0..3
    const int half = wave & 1;       // column half 0..1
    const int l15  = lane & 15;      // A-row / B-col lane index
    const int lq   = lane >> 4;      // k-quad
    const long e0  = (long)blockIdx.x * 256 + g * 64;

    // Per-lane gather byte offsets for this wave's 4 row-tiles.
    int offs[4], offd[4];
#pragma unroll
    for (int rt = 0; rt < 4; rt++) {
        long e = e0 + rt * 16 + l15;
        if (e >= E) e = E - 1;
        int s = eidx[e];
        int d = eidx[(long)E + e];
        s = (s < 0) ? 0 : (s >= n_nodes ? n_nodes - 1 : s);
        d = (d < 0) ? 0 : (d >= n_nodes ? n_nodes - 1 : d);
        offs[rt] = s << 8;   // 256 B per node row
        offd[rt] = d << 8;
    }
    const char* nbase = (const char*)nodes;
    const int lbo = lq * 16;  // lane byte offset inside a 64B k-step

    floatx4 acc[4][4];
#pragma unroll
    for (int rt = 0; rt < 4; rt++)
#pragma unroll
        for (int t = 0; t < 4; t++) acc[rt][t] = (floatx4){0.f, 0.f, 0.f, 0.f};

    short8 a_cur[4], a_nxt[4];
#pragma unroll
    for (int rt = 0; rt < 4; rt++)
        a_cur[rt] = *(const short8*)(nbase + offs[rt] + lbo);  // ks=0 (src)

    for (int ch = 0; ch < 2; ch++) {
        if (ch) __syncthreads();
        // stage chunk ch of W1^T: rows n=0..127, k in [ch*128, ch*128+128)
        // slot swizzle: 16B slot s of row n stored at s ^ (n&15)
#pragma unroll
        for (int i = 0; i < 4; i++) {
            int u = tid + i * 512;            // 0..2047 16B-units
            int n = u >> 4, s = u & 15;
            *(short8*)&sB[n * 128 + ((s ^ n) & 15) * 8] =
                *(const short8*)&w1t[n * 256 + ch * 128 + s * 8];
        }
        __syncthreads();

#pragma unroll
        for (int k2 = 0; k2 < 4; k2++) {
            const int ks = ch * 4 + k2;
            if (ks < 7) {                      // double-buffer next A fragment
                const int ksn = ks + 1;
                const int cb = (ksn & 3) * 64 + lbo;
                const int* of = (ksn < 4) ? offs : offd;
#pragma unroll
                for (int rt = 0; rt < 4; rt++)
                    a_nxt[rt] = *(const short8*)(nbase + of[rt] + cb);
            }
#pragma unroll
            for (int t = 0; t < 4; t++) {
                const int n = (half * 4 + t) * 16 + l15;
                const int sl = (k2 * 4 + lq) ^ l15;   // un-swizzle (n&15 == l15)
                short8 b = *(const short8*)&sB[n * 128 + sl * 8];
#pragma unroll
                for (int rt = 0; rt < 4; rt++)
                    acc[rt][t] = __builtin_amdgcn_mfma_f32_16x16x32_bf16(
                        a_cur[rt], b, acc[rt][t], 0, 0, 0);
            }
#pragma unroll
            for (int rt = 0; rt < 4; rt++) a_cur[rt] = a_nxt[rt];
        }
    }

    // Epilogue: h = relu(acc+b1); partial (h @ W2) over this wave's 64 cols.
    float b1v[4], w20[4], w21[4];
#pragma unroll
    for (int t = 0; t < 4; t++) {
        int c = (half * 4 + t) * 16 + l15;
        b1v[t] = b1[c];
        w20[t] = w2[c * 2];
        w21[t] = w2[c * 2 + 1];
    }
#pragma unroll
    for (int rt = 0; rt < 4; rt++) {
#pragma unroll
        for (int i = 0; i < 4; i++) {
            float p0 = 0.f, p1 = 0.f;
#pragma unroll
            for (int t = 0; t < 4; t++) {
                float h = acc[rt][t][i] + b1v[t];
                h = fmaxf(h, 0.f);
                p0 = fmaf(h, w20[t], p0);
                p1 = fmaf(h, w21[t], p1);
            }
#pragma unroll
            for (int m = 1; m < 16; m <<= 1) {   // reduce over the 16 col-lanes
                p0 += __shfl_xor(p0, m, 64);
                p1 += __shfl_xor(p1, m, 64);
            }
            if (l15 == 0) {
                float2 o; o.x = p0; o.y = p1;
                sP[half][g * 64 + rt * 16 + lq * 4 + i] = o;
            }
        }
    }
    __syncthreads();

    // Combine the two column halves; coalesced 4B stores (512 thr = 256 edges x 2).
    {
        const int el = tid >> 1, chn = tid & 1;
        const long e = (long)blockIdx.x * 256 + el;
        if (e < E) {
            const float* p0 = (const float*)&sP[0][el];
            const float* p1 = (const float*)&sP[1][el];
            out[e * 2 + chn] = p0[chn] + p1[chn] + b2[chn];
        }
    }
}

extern "C" void kernel_launch(void* const* d_in, const int* in_sizes, int n_in,
                              void* d_out, int out_size, void* d_ws, size_t ws_size,
                              hipStream_t stream) {
    const float* node_emb = (const float*)d_in[0];
    const int*   eidx     = (const int*)d_in[1];
    const float* W1       = (const float*)d_in[2];
    const float* b1       = (const float*)d_in[3];
    const float* W2       = (const float*)d_in[4];
    const float* b2       = (const float*)d_in[5];
    float* out = (float*)d_out;

    const int n_node_elems = in_sizes[0];        // N*128
    const int n_nodes = n_node_elems / 128;
    const int E = in_sizes[1] / 2;

    unsigned short* nodes_bf16 = (unsigned short*)d_ws;
    unsigned short* w1t =
        (unsigned short*)((char*)d_ws + (size_t)n_node_elems * 2);

    const int n4 = n_node_elems / 4;
    const int nblk_nodes = (n4 + 255) / 256;
    cvt_kernel<<<nblk_nodes + 8, 256, 0, stream>>>(node_emb, nodes_bf16, n4,
                                                   W1, w1t, nblk_nodes);

    const int nblk = (E + 255) / 256;
    edge_mlp_kernel<<<nblk, 512, 0, stream>>>(nodes_bf16, w1t, eidx,
                                              b1, W2, b2, out, E, n_nodes);
}